// Round 1
// baseline (404.381 us; speedup 1.0000x reference)
//
#include <hip/hip_runtime.h>

// Interleaver, R=2, GRID=256 -> coarse grid 128^3 = 2^21 cells.
// key = (x>>1)<<14 | (y>>1)<<7 | (z>>1) is lexicographic order of base=coords//2,
// so jnp.unique's row index = rank(key) over the presence bitmap.
//
// R5 restructure (single point pass + fusion):
//   winner is now indexed DIRECTLY by key*8+off (2^21*8 ints = 64 MB, memset 0xFF),
//   so mark does atomicOr(bitmap) + atomicMax(winner) in ONE pass over points and
//   the old winner_kernel / rank_base array are gone. rank+coords+pad+gather are
//   fused: each block owns 64 bitmap words, builds its (rank-ordered) cell list in
//   LDS, then streams its CONTIGUOUS agg span with NT float4 stores.
// Pipeline: memset(bitmap 256KB) + memset(winner 64MB) -> mark -> scanall -> rank_gather.
// Duplicate (cell,off) slots: max point index wins (absmax=0.0 verified previously).
// ws assumption: >= ~68 MB (harness poison fills show ~1 GB ws).

#define WORDS 65536u      // 2^21 / 32
#define RBLOCKS 1024      // rank_gather blocks
#define WPB 64u           // bitmap words per rank_gather block (RBLOCKS*WPB == WORDS)

typedef float v4f __attribute__((ext_vector_type(4)));

// One pass over points: presence bit + last-write-wins winner (signed atomicMax).
__global__ void mark_kernel(const int* __restrict__ coords,
                            unsigned* __restrict__ bitmap,
                            int* __restrict__ winner, int n) {
    int i = blockIdx.x * 256 + threadIdx.x;
    if (i >= n) return;
    int cx = coords[3 * i], cy = coords[3 * i + 1], cz = coords[3 * i + 2];
    unsigned key = ((unsigned)(cx >> 1) << 14) | ((unsigned)(cy >> 1) << 7) |
                   (unsigned)(cz >> 1);
    unsigned off = ((unsigned)(cx & 1) << 2) | ((unsigned)(cy & 1) << 1) |
                   (unsigned)(cz & 1);
    atomicOr(&bitmap[key >> 5], 1u << (key & 31));
    atomicMax(&winner[key * 8u + off], i);
}

// Single block: per-64-word-chunk popcount sums (1024 chunks) + exclusive scan,
// total unique count -> *U.
__global__ void scanall_kernel(const unsigned* __restrict__ bitmap,
                               unsigned* __restrict__ chunkExcl,
                               unsigned* __restrict__ U) {
    __shared__ unsigned sh[256];
    int t = threadIdx.x;
    unsigned base = (unsigned)t * 256u;
    unsigned c[4];
    unsigned s = 0;
#pragma unroll
    for (int q = 0; q < 4; ++q) {
        unsigned cq = 0;
#pragma unroll 8
        for (int j = 0; j < 64; ++j) cq += __popc(bitmap[base + (unsigned)(q * 64 + j)]);
        c[q] = cq;
        s += cq;
    }
    unsigned x = s;
    sh[t] = x; __syncthreads();
    for (int d = 1; d < 256; d <<= 1) {
        unsigned y = (t >= d) ? sh[t - d] : 0u;
        __syncthreads();
        x += y; sh[t] = x; __syncthreads();
    }
    unsigned excl = x - s;
    chunkExcl[4 * t + 0] = excl;
    chunkExcl[4 * t + 1] = excl + c[0];
    chunkExcl[4 * t + 2] = excl + c[0] + c[1];
    chunkExcl[4 * t + 3] = excl + c[0] + c[1] + c[2];
    if (t == 255) *U = x;
}

// Fused rank + sorted coarse coords + full agg write (+ pad tails).
// Block b owns words [b*WPB, (b+1)*WPB): phase A builds the rank-ordered cell
// list in LDS and writes coords_out; phase B streams the block's contiguous
// agg rows [rbBase, rbBase+count) with NT float4 stores (32 lanes per row).
__global__ __launch_bounds__(256)
void rank_gather_kernel(const unsigned* __restrict__ bitmap,
                        const unsigned* __restrict__ chunkExcl,
                        const unsigned* __restrict__ Uptr,
                        const int* __restrict__ winner,
                        const float* __restrict__ feats,
                        float* __restrict__ coords_out,
                        float* __restrict__ agg, int n) {
    __shared__ unsigned shCell[WPB * 32u];
    __shared__ unsigned shScan[WPB];
    __shared__ unsigned shCount;
    int t = threadIdx.x;
    unsigned wbase = blockIdx.x * WPB;
    unsigned rbBase = chunkExcl[blockIdx.x];

    // --- phase A: block-local scan of popcounts, emit cell list + coords ---
    unsigned word = 0, cnt = 0;
    if (t < (int)WPB) {
        word = bitmap[wbase + (unsigned)t];
        cnt = __popc(word);
        shScan[t] = cnt;
    }
    __syncthreads();
    unsigned x = cnt;
    for (int d = 1; d < (int)WPB; d <<= 1) {
        unsigned y = (t < (int)WPB && t >= d) ? shScan[t - d] : 0u;
        __syncthreads();
        if (t < (int)WPB) { x += y; shScan[t] = x; }
        __syncthreads();
    }
    if (t == (int)WPB - 1) shCount = x;
    if (t < (int)WPB) {
        unsigned listpos = x - cnt;          // exclusive offset within block
        unsigned rb = rbBase + listpos;
        unsigned wtmp = word;
        while (wtmp) {
            int k = __ffs(wtmp) - 1;
            wtmp &= wtmp - 1;
            unsigned cell = (wbase + (unsigned)t) * 32u + (unsigned)k;
            shCell[listpos] = cell;
            coords_out[3 * rb + 0] = (float)(cell >> 14);
            coords_out[3 * rb + 1] = (float)((cell >> 7) & 127u);
            coords_out[3 * rb + 2] = (float)(cell & 127u);
            ++listpos; ++rb;
        }
    }
    __syncthreads();
    unsigned count = shCount;

    // --- phase B: stream the block's contiguous agg span, NT float4 ---
    const v4f* feats4 = (const v4f*)feats;
    v4f* agg4 = (v4f*)agg;
    int grp = t >> 5;          // 8 row-groups of 32 lanes
    int lane = t & 31;         // float4 index within the 128-float row
    int off = lane >> 2;       // intra-cell slot 0..7
    int c4 = lane & 3;         // float4 within the 16-float feature vector
    for (unsigned idx = (unsigned)grp; idx < count; idx += 8u) {
        unsigned cell = shCell[idx];
        int w = winner[cell * 8u + (unsigned)off];
        v4f v = (v4f)(0.f);
        if (w >= 0) v = feats4[(size_t)w * 4 + c4];
        __builtin_nontemporal_store(v, agg4 + (size_t)(rbBase + idx) * 32 + lane);
    }

    // --- pad tails: rows in [U, n) -> coords=-1, agg=0 (grid-stride) ---
    unsigned Uv = *Uptr;
    unsigned gid = blockIdx.x * 256u + (unsigned)t;
    unsigned nth = gridDim.x * 256u;
    for (unsigned r = Uv + gid; r < (unsigned)n; r += nth) {
        coords_out[3 * r + 0] = -1.0f;
        coords_out[3 * r + 1] = -1.0f;
        coords_out[3 * r + 2] = -1.0f;
    }
    v4f z = (v4f)(0.f);
    for (size_t j = (size_t)Uv * 32 + gid; j < (size_t)n * 32; j += nth) {
        __builtin_nontemporal_store(z, agg4 + j);
    }
}

extern "C" void kernel_launch(void* const* d_in, const int* in_sizes, int n_in,
                              void* d_out, int out_size, void* d_ws, size_t ws_size,
                              hipStream_t stream) {
    const float* feats = (const float*)d_in[0];   // [N,16] f32
    const int* coords  = (const int*)d_in[1];     // [N,3]  i32
    int n = in_sizes[1] / 3;

    float* out        = (float*)d_out;
    float* coords_out = out;                      // [N,3]  (floats; -1 padding)
    float* agg        = out + (size_t)3 * n;      // [N,128]

    // ws: bitmap[65536] | chunkExcl[1024] | U[1(+3 pad)] | winner[2^21 * 8] (64 MB)
    unsigned* bitmap    = (unsigned*)d_ws;
    unsigned* chunkExcl = bitmap + WORDS;
    unsigned* U         = chunkExcl + 1024;
    int*      winner    = (int*)(U + 4);          // 16B-aligned

    (void)hipMemsetAsync(bitmap, 0, WORDS * sizeof(unsigned), stream);
    (void)hipMemsetAsync(winner, 0xFF, (size_t)WORDS * 32u * 8u * sizeof(int), stream);

    int nb = (n + 255) / 256;
    mark_kernel<<<nb, 256, 0, stream>>>(coords, bitmap, winner, n);
    scanall_kernel<<<1, 256, 0, stream>>>(bitmap, chunkExcl, U);
    rank_gather_kernel<<<RBLOCKS, 256, 0, stream>>>(bitmap, chunkExcl, U, winner,
                                                    feats, coords_out, agg, n);
}

// Round 2
// 391.091 us; speedup vs baseline: 1.0340x; 1.0340x over previous
//
#include <hip/hip_runtime.h>

// Interleaver, R=2, GRID=256 -> coarse grid 128^3 = 2^21 cells.
// key = (x>>1)<<14 | (y>>1)<<7 | (z>>1) is lexicographic order of base=coords//2,
// so jnp.unique's row index = rank(key) over the presence bitmap.
//
// R6 = R5's single point pass + R4's dense gather:
//   - winner directly indexed by key*8+off (2^21*8 u32 = 64 MB), value = point
//     index + 1, 0 = empty -> bitmap+winner init is ONE contiguous memset(0).
//   - mark: atomicOr(bitmap) + atomicMax(winner) in one pass over points.
//   - rank kernel emits rank-ordered cells[] (2 MB) alongside coords_out, and
//     writes the pad tails (cells=SENTINEL, coords=-1).
//   - gather: 16M threads, one float4 each (R4's proven-fast shape); row->cell
//     via coalesced cells[] broadcast; SENTINEL rows stream zeros.
// Pipeline (5 dispatches): memset(64.25MB) -> mark -> scanall -> rank -> gather.
// Duplicate (cell,off) slots (= identical coords): max point index wins
// (absmax=0.0 verified in earlier rounds).

#define WORDS 65536u          // 2^21 / 32
#define SENTINEL 0xFFFFFFFFu

typedef float v4f __attribute__((ext_vector_type(4)));

// One pass over points: presence bit + last-write-wins winner (i+1, atomicMax).
__global__ void mark_kernel(const int* __restrict__ coords,
                            unsigned* __restrict__ bitmap,
                            unsigned* __restrict__ winner, int n) {
    int i = blockIdx.x * 256 + threadIdx.x;
    if (i >= n) return;
    int cx = coords[3 * i], cy = coords[3 * i + 1], cz = coords[3 * i + 2];
    unsigned key = ((unsigned)(cx >> 1) << 14) | ((unsigned)(cy >> 1) << 7) |
                   (unsigned)(cz >> 1);
    unsigned off = ((unsigned)(cx & 1) << 2) | ((unsigned)(cy & 1) << 1) |
                   (unsigned)(cz & 1);
    atomicOr(&bitmap[key >> 5], 1u << (key & 31));
    atomicMax(&winner[key * 8u + off], (unsigned)i + 1u);
}

// Single block: per-256-word-chunk popcount sums + exclusive scan -> chunkExcl,
// total unique count -> *U. uint4 loads (16B) to cut the load count 4x.
__global__ void scanall_kernel(const unsigned* __restrict__ bitmap,
                               unsigned* __restrict__ chunkExcl,
                               unsigned* __restrict__ U) {
    __shared__ unsigned sh[256];
    int t = threadIdx.x;
    const uint4* b4 = (const uint4*)bitmap;
    unsigned base = (unsigned)t * 64u;        // 64 uint4 = 256 words per chunk
    unsigned s = 0;
#pragma unroll 8
    for (unsigned j = 0; j < 64u; ++j) {
        uint4 v = b4[base + j];
        s += __popc(v.x) + __popc(v.y) + __popc(v.z) + __popc(v.w);
    }
    unsigned x = s;
    sh[t] = x; __syncthreads();
    for (int d = 1; d < 256; d <<= 1) {
        unsigned y = (t >= d) ? sh[t - d] : 0u;
        __syncthreads();
        x += y; sh[t] = x; __syncthreads();
    }
    chunkExcl[t] = x - s;
    if (t == 255) *U = x;
}

// Rank-ordered cell list + sorted coarse coords (rows < U) + pad tails (>= U).
__global__ __launch_bounds__(256)
void rank_kernel(const unsigned* __restrict__ bitmap,
                 const unsigned* __restrict__ chunkExcl,
                 const unsigned* __restrict__ Uptr,
                 unsigned* __restrict__ cells,
                 float* __restrict__ coords_out, int n) {
    __shared__ unsigned sh[256];
    int t = threadIdx.x;
    unsigned w = blockIdx.x * 256 + t;
    unsigned word = bitmap[w];
    unsigned cnt = __popc(word);
    unsigned x = cnt;
    sh[t] = x; __syncthreads();
    for (int d = 1; d < 256; d <<= 1) {
        unsigned y = (t >= d) ? sh[t - d] : 0u;
        __syncthreads();
        x += y; sh[t] = x; __syncthreads();
    }
    unsigned rb = chunkExcl[blockIdx.x] + x - cnt;
    while (word) {
        int k = __ffs(word) - 1;
        word &= word - 1;
        unsigned cell = w * 32u + (unsigned)k;
        cells[rb] = cell;
        coords_out[3 * rb + 0] = (float)(cell >> 14);
        coords_out[3 * rb + 1] = (float)((cell >> 7) & 127u);
        coords_out[3 * rb + 2] = (float)(cell & 127u);
        ++rb;
    }
    // pad: rows in [U, n) -> cells=SENTINEL, coords=-1 (65536 threads total)
    unsigned Uv = *Uptr;
    unsigned gid = blockIdx.x * 256u + (unsigned)t;
    unsigned nth = gridDim.x * 256u;
    for (unsigned r = Uv + gid; r < (unsigned)n; r += nth) {
        cells[r] = SENTINEL;
        coords_out[3 * r + 0] = -1.0f;
        coords_out[3 * r + 1] = -1.0f;
        coords_out[3 * r + 2] = -1.0f;
    }
}

// Dense: one float4 per thread over the whole agg, NT streaming stores.
__global__ void gather_kernel(const float* __restrict__ feats,
                              const unsigned* __restrict__ winner,
                              const unsigned* __restrict__ cells,
                              float* __restrict__ agg, int total4) {
    int j = blockIdx.x * 256 + threadIdx.x;
    if (j >= total4) return;
    unsigned row = (unsigned)j >> 5;          // 32 float4 per 128-float row
    unsigned cell = cells[row];               // coalesced broadcast
    v4f v = (v4f)(0.f);
    if (cell != SENTINEL) {
        unsigned off = ((unsigned)j >> 2) & 7u;
        unsigned w = winner[cell * 8u + off];
        if (w) {
            unsigned c4 = (unsigned)j & 3u;
            v = ((const v4f*)feats)[(size_t)(w - 1u) * 4u + c4];
        }
    }
    __builtin_nontemporal_store(v, (v4f*)agg + j);
}

extern "C" void kernel_launch(void* const* d_in, const int* in_sizes, int n_in,
                              void* d_out, int out_size, void* d_ws, size_t ws_size,
                              hipStream_t stream) {
    const float* feats = (const float*)d_in[0];   // [N,16] f32
    const int* coords  = (const int*)d_in[1];     // [N,3]  i32
    int n = in_sizes[1] / 3;

    float* out        = (float*)d_out;
    float* coords_out = out;                      // [N,3]  (floats; -1 padding)
    float* agg        = out + (size_t)3 * n;      // [N,128]

    // ws: bitmap[65536] | winner[2^21*8] | chunkExcl[256] | U[1+3] | cells[n]
    unsigned* bitmap    = (unsigned*)d_ws;
    unsigned* winner    = bitmap + WORDS;                       // 64 MB
    unsigned* chunkExcl = winner + (size_t)WORDS * 256u;        // 2^21*8 u32
    unsigned* U         = chunkExcl + 256;
    unsigned* cells     = U + 4;                                // 16B-aligned

    // bitmap(0) + winner(0 = empty) are contiguous: ONE memset, 64.25 MB.
    (void)hipMemsetAsync(d_ws, 0, (size_t)(WORDS + (size_t)WORDS * 256u) * 4u,
                         stream);

    int nb = (n + 255) / 256;
    mark_kernel<<<nb, 256, 0, stream>>>(coords, bitmap, winner, n);
    scanall_kernel<<<1, 256, 0, stream>>>(bitmap, chunkExcl, U);
    rank_kernel<<<WORDS / 256, 256, 0, stream>>>(bitmap, chunkExcl, U, cells,
                                                 coords_out, n);
    int total4 = n * 32;                          // n*128 floats / 4
    gather_kernel<<<(total4 + 255) / 256, 256, 0, stream>>>(feats, winner, cells,
                                                            agg, total4);
}

// Round 3
// 361.444 us; speedup vs baseline: 1.1188x; 1.0820x over previous
//
#include <hip/hip_runtime.h>

// Interleaver, R=2, GRID=256 -> coarse grid 128^3 = 2^21 cells.
// key = (x>>1)<<14 | (y>>1)<<7 | (z>>1) is lexicographic order of base=coords//2,
// so jnp.unique's row index = rank(key) over the presence bitmap.
//
// R7 = R4 skeleton (rank-indexed winner, dense gather) minus its stalls:
//   - scanall fused into rankscan: each of 256 blocks reads the whole 256 KB
//     bitmap (uint4, L2-resident) and self-computes the global chunk prefix --
//     no single-block serialization, no *U dependency.
//   - mark emits packed keys[] (2 MB) so the winner pass reads 2 MB instead of
//     re-reading 6 MB coords.
//   - winner init (0 = empty; stores i+1) fused with bitmap into ONE contiguous
//     16.25 MB memset.
// Pipeline (5 dispatches): memset -> mark -> rankscan -> winner -> gather.
// Duplicate (cell,off) slots (= identical coords): max point index wins
// (absmax=0.0 harness-verified in earlier rounds).

#define WORDS 65536u          // 2^21 / 32

typedef float v4f __attribute__((ext_vector_type(4)));

// One pass over points: presence bit + packed (key<<3|off) for later passes.
__global__ void mark_kernel(const int* __restrict__ coords,
                            unsigned* __restrict__ bitmap,
                            unsigned* __restrict__ keys, int n) {
    int i = blockIdx.x * 256 + threadIdx.x;
    if (i >= n) return;
    int cx = coords[3 * i], cy = coords[3 * i + 1], cz = coords[3 * i + 2];
    unsigned key = ((unsigned)(cx >> 1) << 14) | ((unsigned)(cy >> 1) << 7) |
                   (unsigned)(cz >> 1);
    unsigned off = ((unsigned)(cx & 1) << 2) | ((unsigned)(cy & 1) << 1) |
                   (unsigned)(cz & 1);
    keys[i] = (key << 3) | off;
    atomicOr(&bitmap[key >> 5], 1u << (key & 31));
}

// Fused global-scan + rank: 256 blocks. Phase 1: every block reads the FULL
// bitmap (thread t sums chunk t's 256 words via uint4) and LDS-scans the 256
// chunk sums -> this block's global chunk-exclusive prefix + total U.
// Phase 2: intra-chunk word scan -> rank_base[w] + sorted coarse coords.
// Pad tails (rows >= U) written grid-stride by all 65536 threads.
__global__ __launch_bounds__(256)
void rankscan_kernel(const unsigned* __restrict__ bitmap,
                     unsigned* __restrict__ rank_base,
                     float* __restrict__ coords_out, int n) {
    __shared__ unsigned sh[256];
    __shared__ unsigned shChunkExcl, shU;
    int t = threadIdx.x;
    int b = blockIdx.x;

    // --- phase 1: full-bitmap chunk sums + scan (all blocks, parallel) ---
    const uint4* b4 = (const uint4*)bitmap;
    unsigned base = (unsigned)t * 64u;        // 64 uint4 = 256 words per chunk
    unsigned s = 0;
#pragma unroll 8
    for (unsigned j = 0; j < 64u; ++j) {
        uint4 v = b4[base + j];
        s += __popc(v.x) + __popc(v.y) + __popc(v.z) + __popc(v.w);
    }
    unsigned x = s;
    sh[t] = x; __syncthreads();
    for (int d = 1; d < 256; d <<= 1) {
        unsigned y = (t >= d) ? sh[t - d] : 0u;
        __syncthreads();
        x += y; sh[t] = x; __syncthreads();
    }
    if (t == b) shChunkExcl = x - s;          // exclusive prefix of chunk b
    if (t == 255) shU = x;                    // total unique count
    __syncthreads();
    unsigned chunkExcl = shChunkExcl;
    unsigned U = shU;
    __syncthreads();

    // --- phase 2: intra-chunk word scan for this block's 256 words ---
    unsigned w = (unsigned)b * 256u + (unsigned)t;
    unsigned word = bitmap[w];
    unsigned cnt = __popc(word);
    x = cnt;
    sh[t] = x; __syncthreads();
    for (int d = 1; d < 256; d <<= 1) {
        unsigned y = (t >= d) ? sh[t - d] : 0u;
        __syncthreads();
        x += y; sh[t] = x; __syncthreads();
    }
    unsigned rb = chunkExcl + x - cnt;
    rank_base[w] = rb;
    while (word) {
        int k = __ffs(word) - 1;
        word &= word - 1;
        unsigned cell = w * 32u + (unsigned)k;
        coords_out[3 * rb + 0] = (float)(cell >> 14);
        coords_out[3 * rb + 1] = (float)((cell >> 7) & 127u);
        coords_out[3 * rb + 2] = (float)(cell & 127u);
        ++rb;
    }
    // pad: rows in [U, n) -> coords = -1 (65536 threads grid-stride)
    unsigned gid = (unsigned)b * 256u + (unsigned)t;
    unsigned nth = gridDim.x * 256u;
    for (unsigned r = U + gid; r < (unsigned)n; r += nth) {
        coords_out[3 * r + 0] = -1.0f;
        coords_out[3 * r + 1] = -1.0f;
        coords_out[3 * r + 2] = -1.0f;
    }
}

// Last-write-wins via atomicMax of (i+1) into the rank-indexed winner array.
__global__ void winner_kernel(const unsigned* __restrict__ keys,
                              const unsigned* __restrict__ bitmap,
                              const unsigned* __restrict__ rank_base,
                              unsigned* __restrict__ winner, int n) {
    int i = blockIdx.x * 256 + threadIdx.x;
    if (i >= n) return;
    unsigned pk = keys[i];
    unsigned key = pk >> 3, off = pk & 7u;
    unsigned wd = key >> 5;
    unsigned r = rank_base[wd] + __popc(bitmap[wd] & ((1u << (key & 31)) - 1u));
    atomicMax(&winner[r * 8u + off], (unsigned)i + 1u);
}

// Dense: one float4 per thread over the whole agg, NT streaming stores.
// winner covers ALL n rows (memset 0), so pad rows naturally stream zeros.
__global__ void gather_kernel(const float* __restrict__ feats,
                              const unsigned* __restrict__ winner,
                              float* __restrict__ agg, int total4) {
    int j = blockIdx.x * 256 + threadIdx.x;   // one float4 per thread
    if (j >= total4) return;
    int slot = j >> 2;                        // (row*8 + off)
    int c4 = j & 3;
    unsigned w = __builtin_nontemporal_load(&winner[slot]);
    v4f v = (v4f)(0.f);
    if (w) v = ((const v4f*)feats)[(size_t)(w - 1u) * 4u + c4];
    __builtin_nontemporal_store(v, (v4f*)agg + j);
}

extern "C" void kernel_launch(void* const* d_in, const int* in_sizes, int n_in,
                              void* d_out, int out_size, void* d_ws, size_t ws_size,
                              hipStream_t stream) {
    const float* feats = (const float*)d_in[0];   // [N,16] f32
    const int* coords  = (const int*)d_in[1];     // [N,3]  i32
    int n = in_sizes[1] / 3;

    float* out        = (float*)d_out;
    float* coords_out = out;                      // [N,3]  (floats; -1 padding)
    float* agg        = out + (size_t)3 * n;      // [N,128]

    // ws: bitmap[65536] | winner[8n] | rank_base[65536] | keys[n]
    unsigned* bitmap    = (unsigned*)d_ws;
    unsigned* winner    = bitmap + WORDS;             // 8n u32 (16 MB @ n=500K)
    unsigned* rank_base = winner + (size_t)8 * n;
    unsigned* keys      = rank_base + WORDS;

    // bitmap(0) + winner(0 = empty) are contiguous: ONE memset, ~16.25 MB.
    (void)hipMemsetAsync(d_ws, 0, (WORDS + (size_t)8 * n) * sizeof(unsigned),
                         stream);

    int nb = (n + 255) / 256;
    mark_kernel<<<nb, 256, 0, stream>>>(coords, bitmap, keys, n);
    rankscan_kernel<<<WORDS / 256, 256, 0, stream>>>(bitmap, rank_base,
                                                     coords_out, n);
    winner_kernel<<<nb, 256, 0, stream>>>(keys, bitmap, rank_base, winner, n);
    int total4 = n * 32;                          // n*128 floats / 4
    gather_kernel<<<(total4 + 255) / 256, 256, 0, stream>>>(feats, winner, agg,
                                                            total4);
}

// Round 4
// 361.198 us; speedup vs baseline: 1.1196x; 1.0007x over previous
//
#include <hip/hip_runtime.h>

// Interleaver, R=2, GRID=256 -> coarse grid 128^3 = 2^21 cells.
// key = (x>>1)<<14 | (y>>1)<<7 | (z>>1) is lexicographic order of base=coords//2,
// so jnp.unique's row index = rank(key) over the presence bitmap.
//
// R8 = R7 minus the last non-mandatory costs:
//   - winner init fused into mark as grid-stride uint4 zero-stores (overlaps
//     the coords read); the standalone memset shrinks to bitmap-only (256 KB).
//   - rankscan's two 256-element LDS ladder scans (32 barriers) replaced with
//     __shfl_up wave scans + 4-element LDS combine (~3 barriers).
// Pipeline (5 dispatches): memset(256KB) -> mark -> rankscan -> winner -> gather.
// Duplicate (cell,off) slots (= identical coords): max point index wins
// (absmax=0.0 harness-verified in earlier rounds).

#define WORDS 65536u          // 2^21 / 32

typedef float v4f __attribute__((ext_vector_type(4)));

// One pass over points: winner[8n]=0 init (uint4), packed key emit, presence bit.
__global__ void mark_kernel(const int* __restrict__ coords,
                            unsigned* __restrict__ bitmap,
                            unsigned* __restrict__ keys,
                            uint4* __restrict__ winner4, int n) {
    int i = blockIdx.x * 256 + threadIdx.x;
    int nth = gridDim.x * 256;
    uint4 z = {0u, 0u, 0u, 0u};
    for (int s = i; s < 2 * n; s += nth) winner4[s] = z;   // winner[8n] = 0
    if (i >= n) return;
    int cx = coords[3 * i], cy = coords[3 * i + 1], cz = coords[3 * i + 2];
    unsigned key = ((unsigned)(cx >> 1) << 14) | ((unsigned)(cy >> 1) << 7) |
                   (unsigned)(cz >> 1);
    unsigned off = ((unsigned)(cx & 1) << 2) | ((unsigned)(cy & 1) << 1) |
                   (unsigned)(cz & 1);
    keys[i] = (key << 3) | off;
    atomicOr(&bitmap[key >> 5], 1u << (key & 31));
}

// Fused global-scan + rank, 256 blocks. Phase 1: every block reads the FULL
// bitmap (thread t sums chunk t's 256 words via uint4), shfl-scans the 256
// chunk sums -> this block's global chunk-exclusive prefix + total U.
// Phase 2: intra-chunk word shfl-scan -> rank_base[w] + sorted coarse coords.
// Pad tails (rows >= U) written grid-stride by all 65536 threads.
__global__ __launch_bounds__(256)
void rankscan_kernel(const unsigned* __restrict__ bitmap,
                     unsigned* __restrict__ rank_base,
                     float* __restrict__ coords_out, int n) {
    __shared__ unsigned wsum[4];
    __shared__ unsigned shExcl, shU;
    int t = threadIdx.x;
    int b = blockIdx.x;
    int lane = t & 63, wv = t >> 6;

    // --- phase 1: full-bitmap chunk sums + barrier-light scan ---
    const uint4* b4 = (const uint4*)bitmap;
    unsigned base = (unsigned)t * 64u;        // 64 uint4 = 256 words per chunk
    unsigned s = 0;
#pragma unroll 8
    for (unsigned j = 0; j < 64u; ++j) {
        uint4 v = b4[base + j];
        s += __popc(v.x) + __popc(v.y) + __popc(v.z) + __popc(v.w);
    }
    unsigned x = s;
    for (int d = 1; d < 64; d <<= 1) {        // per-wave inclusive scan
        unsigned y = __shfl_up(x, d);
        if (lane >= d) x += y;
    }
    if (lane == 63) wsum[wv] = x;
    __syncthreads();
    unsigned add = 0;
    for (int k = 0; k < wv; ++k) add += wsum[k];
    x += add;                                  // inclusive over all 256 chunks
    if (t == b) shExcl = x - s;                // exclusive prefix of chunk b
    if (t == 255) shU = x;                     // total unique count
    __syncthreads();
    unsigned chunkExcl = shExcl;
    unsigned U = shU;
    __syncthreads();                           // wsum reused below

    // --- phase 2: intra-chunk word scan for this block's 256 words ---
    unsigned w = (unsigned)b * 256u + (unsigned)t;
    unsigned word = bitmap[w];
    unsigned cnt = __popc(word);
    x = cnt;
    for (int d = 1; d < 64; d <<= 1) {
        unsigned y = __shfl_up(x, d);
        if (lane >= d) x += y;
    }
    if (lane == 63) wsum[wv] = x;
    __syncthreads();
    add = 0;
    for (int k = 0; k < wv; ++k) add += wsum[k];
    x += add;
    unsigned rb = chunkExcl + x - cnt;
    rank_base[w] = rb;
    while (word) {
        int k = __ffs(word) - 1;
        word &= word - 1;
        unsigned cell = w * 32u + (unsigned)k;
        coords_out[3 * rb + 0] = (float)(cell >> 14);
        coords_out[3 * rb + 1] = (float)((cell >> 7) & 127u);
        coords_out[3 * rb + 2] = (float)(cell & 127u);
        ++rb;
    }
    // pad: rows in [U, n) -> coords = -1 (65536 threads grid-stride)
    unsigned gid = (unsigned)b * 256u + (unsigned)t;
    unsigned nth = gridDim.x * 256u;
    for (unsigned r = U + gid; r < (unsigned)n; r += nth) {
        coords_out[3 * r + 0] = -1.0f;
        coords_out[3 * r + 1] = -1.0f;
        coords_out[3 * r + 2] = -1.0f;
    }
}

// Last-write-wins via atomicMax of (i+1) into the rank-indexed winner array.
__global__ void winner_kernel(const unsigned* __restrict__ keys,
                              const unsigned* __restrict__ bitmap,
                              const unsigned* __restrict__ rank_base,
                              unsigned* __restrict__ winner, int n) {
    int i = blockIdx.x * 256 + threadIdx.x;
    if (i >= n) return;
    unsigned pk = keys[i];
    unsigned key = pk >> 3, off = pk & 7u;
    unsigned wd = key >> 5;
    unsigned r = rank_base[wd] + __popc(bitmap[wd] & ((1u << (key & 31)) - 1u));
    atomicMax(&winner[r * 8u + off], (unsigned)i + 1u);
}

// Dense: one float4 per thread over the whole agg, NT streaming stores.
// winner covers ALL n rows (zeroed in mark), so pad rows stream zeros.
__global__ void gather_kernel(const float* __restrict__ feats,
                              const unsigned* __restrict__ winner,
                              float* __restrict__ agg, int total4) {
    int j = blockIdx.x * 256 + threadIdx.x;   // one float4 per thread
    if (j >= total4) return;
    int slot = j >> 2;                        // (row*8 + off)
    int c4 = j & 3;
    unsigned w = __builtin_nontemporal_load(&winner[slot]);
    v4f v = (v4f)(0.f);
    if (w) v = ((const v4f*)feats)[(size_t)(w - 1u) * 4u + c4];
    __builtin_nontemporal_store(v, (v4f*)agg + j);
}

extern "C" void kernel_launch(void* const* d_in, const int* in_sizes, int n_in,
                              void* d_out, int out_size, void* d_ws, size_t ws_size,
                              hipStream_t stream) {
    const float* feats = (const float*)d_in[0];   // [N,16] f32
    const int* coords  = (const int*)d_in[1];     // [N,3]  i32
    int n = in_sizes[1] / 3;

    float* out        = (float*)d_out;
    float* coords_out = out;                      // [N,3]  (floats; -1 padding)
    float* agg        = out + (size_t)3 * n;      // [N,128]

    // ws: bitmap[65536] | winner[8n] | rank_base[65536] | keys[n]
    unsigned* bitmap    = (unsigned*)d_ws;
    unsigned* winner    = bitmap + WORDS;             // 8n u32 (16 MB @ n=500K)
    unsigned* rank_base = winner + (size_t)8 * n;
    unsigned* keys      = rank_base + WORDS;

    (void)hipMemsetAsync(bitmap, 0, WORDS * sizeof(unsigned), stream);

    int nb = (n + 255) / 256;
    mark_kernel<<<nb, 256, 0, stream>>>(coords, bitmap, keys, (uint4*)winner, n);
    rankscan_kernel<<<WORDS / 256, 256, 0, stream>>>(bitmap, rank_base,
                                                     coords_out, n);
    winner_kernel<<<nb, 256, 0, stream>>>(keys, bitmap, rank_base, winner, n);
    int total4 = n * 32;                          // n*128 floats / 4
    gather_kernel<<<(total4 + 255) / 256, 256, 0, stream>>>(feats, winner, agg,
                                                            total4);
}